// Round 4
// baseline (871.153 us; speedup 1.0000x reference)
//
#include <hip/hip_runtime.h>
#include <hip/hip_bf16.h>
#include <stdint.h>

typedef uint16_t u16;
typedef uint32_t u32;
typedef uint64_t u64;
typedef short bf16x8 __attribute__((ext_vector_type(8)));   // 8 bf16 in 4 VGPRs
typedef float f32x2 __attribute__((ext_vector_type(2)));
typedef float f32x4 __attribute__((ext_vector_type(4)));
typedef u32 u32x4 __attribute__((ext_vector_type(4)));

#define E_N 131072
#define T_N 1048576

__device__ __forceinline__ float bf2f(u32 u) { return __builtin_bit_cast(float, u << 16); }
__device__ __forceinline__ u16 f2bf(float f) {
  u32 u = __builtin_bit_cast(u32, f);
  return (u16)((u + 0x7fffu + ((u >> 16) & 1u)) >> 16);   // RNE
}
__device__ __forceinline__ float silu_f(float x) { return x / (1.0f + __expf(-x)); }
__device__ __forceinline__ f32x4 mfma16(bf16x8 a, bf16x8 b, f32x4 c) {
  return __builtin_amdgcn_mfma_f32_16x16x32_bf16(a, b, c, 0, 0, 0);
}
__device__ __forceinline__ void gld_lds16(const void* g, void* l) {
  __builtin_amdgcn_global_load_lds((const __attribute__((address_space(1))) u32*)g,
                                   (__attribute__((address_space(3))) u32*)l, 16, 0, 0);
}
#define WAIT_LGKM0() do { asm volatile("s_waitcnt lgkmcnt(0)" ::: "memory"); \
                          __builtin_amdgcn_sched_barrier(0); } while (0)
#define WAIT_VM0()   do { asm volatile("s_waitcnt vmcnt(0)" ::: "memory"); \
                          __builtin_amdgcn_sched_barrier(0); } while (0)

// ---------------------------------------------------------------------------
// T0: convert+transpose all f32 weight matrices into ws as [n][k] row-major bf16.
__global__ __launch_bounds__(256) void k_transpose(
    const float* __restrict__ Wji, const float* __restrict__ Wkj, const float* __restrict__ Wbil,
    const float* __restrict__ w11, const float* __restrict__ w12,
    const float* __restrict__ w21, const float* __restrict__ w22, const float* __restrict__ wout,
    u16* __restrict__ dst) {
  u32 idx = blockIdx.x * 256 + threadIdx.x;
  if (idx < 32768) {
    u32 n = idx >> 7, h = idx & 127;
    dst[idx] = f2bf((n < 128) ? Wji[h * 128 + n] : Wkj[h * 128 + (n - 128)]);
  } else if (idx < 32768 + 131072) {
    u32 q = idx - 32768;
    u32 b = q >> 14, n = (q >> 7) & 127, h = q & 127;
    dst[idx] = f2bf(Wbil[h * 1024 + b * 128 + n]);
  } else if (idx < 245760) {
    u32 q = idx - 163840;
    u32 r = q >> 14, n = (q >> 7) & 127, h = q & 127;
    const float* src = (r == 0) ? w11 : (r == 1) ? w12 : (r == 2) ? w21 : (r == 3) ? w22 : wout;
    dst[idx] = f2bf(src[h * 128 + n]);
  }
}

// ---------------------------------------------------------------------------
// Counting sort of triplets by ji (17-bit key over E_N bins).
__global__ __launch_bounds__(256) void k_hist(const int* __restrict__ trip, int* __restrict__ cnt) {
  u32 t = blockIdx.x * 256 + threadIdx.x;
  atomicAdd(&cnt[trip[T_N + t]], 1);
}
__global__ __launch_bounds__(256) void k_scanA(const int* __restrict__ cnt,
                                               int* __restrict__ offsA, int* __restrict__ blksum) {
  __shared__ int s[256];
  u32 b = blockIdx.x, tid = threadIdx.x;
  int v = cnt[b * 256 + tid];
  s[tid] = v; __syncthreads();
  for (int d = 1; d < 256; d <<= 1) {
    int t = (tid >= (u32)d) ? s[tid - d] : 0;
    __syncthreads(); s[tid] += t; __syncthreads();
  }
  offsA[b * 256 + tid] = s[tid] - v;
  if (tid == 255) blksum[b] = s[255];
}
__global__ __launch_bounds__(512) void k_scanB(const int* __restrict__ blksum, int* __restrict__ blkoff) {
  __shared__ int s[512];
  u32 tid = threadIdx.x;
  int v = blksum[tid];
  s[tid] = v; __syncthreads();
  for (int d = 1; d < 512; d <<= 1) {
    int t = (tid >= (u32)d) ? s[tid - d] : 0;
    __syncthreads(); s[tid] += t; __syncthreads();
  }
  blkoff[tid] = s[tid] - v;
}
__global__ __launch_bounds__(256) void k_scanC(const int* __restrict__ offsA,
                                               const int* __restrict__ blkoff, int* __restrict__ offs_work) {
  u32 i = blockIdx.x * 256 + threadIdx.x;
  offs_work[i] = offsA[i] + blkoff[blockIdx.x];
}
__global__ __launch_bounds__(256) void k_place(const int* __restrict__ trip,
                                               int* __restrict__ offs_work, int* __restrict__ tsort) {
  u32 t = blockIdx.x * 256 + threadIdx.x;
  int e = trip[T_N + t];
  int p = atomicAdd(&offs_work[e], 1);
  tsort[p] = (int)t;
}

// ---------------------------------------------------------------------------
// S2: per-edge pre-GEMM.  [128 rows] x W2T[256][128].
__global__ __launch_bounds__(512) void k_pre(
    const float* __restrict__ m, const float* __restrict__ rbf, const float* __restrict__ Wrbf,
    const float* __restrict__ bkj, const float* __restrict__ bji,
    const char* __restrict__ W2T, float* __restrict__ aggr, u16* __restrict__ ek) {
  extern __shared__ char lds[];
  char* ldsA = lds;                              // 32768
  char* ldsB = lds + 32768;                      // 65536
  float* ldsRbf = (float*)(lds + 98304);         // [128][6]
  float* ldsWr = (float*)(lds + 101376);         // [6][128]
  const u32 tid = threadIdx.x, lane = tid & 63;
  const u32 r0 = blockIdx.x << 7;

#pragma unroll
  for (int it = 0; it < 8; ++it) {
    u32 q = tid + it * 512;
    u32 row = q >> 5, c4 = q & 31;
    f32x4 v = *(const f32x4*)(m + (size_t)(r0 + row) * 128 + c4 * 4);
    u32 c = c4 >> 1, half = c4 & 1;
    u32 w0 = (u32)f2bf(v[0]) | ((u32)f2bf(v[1]) << 16);
    u32 w1 = (u32)f2bf(v[2]) | ((u32)f2bf(v[3]) << 16);
    u32 ofs = (row << 8) + ((c ^ (row & 7)) << 4) + half * 8;
    *(u64*)(ldsA + ofs) = (u64)w0 | ((u64)w1 << 32);
  }
#pragma unroll
  for (int it = 0; it < 8; ++it) {
    u32 q = tid + it * 512, n = q >> 4, c = q & 15;
    gld_lds16(W2T + n * 256 + ((c ^ (n & 7)) << 4), ldsB + q * 16);
  }
  for (u32 i = tid; i < 768; i += 512) ldsRbf[i] = rbf[(size_t)r0 * 6 + i];
  for (u32 i = tid; i < 768; i += 512) ldsWr[i] = Wrbf[i];
  __syncthreads();

  const u32 wid = tid >> 6, wm = wid >> 2, wn = wid & 3;
  const u32 rb = wm << 6, cb = wn << 6;
  f32x4 acc[4][4] = {};
  bf16x8 Bf[4][4];
#pragma unroll
  for (int ni = 0; ni < 4; ++ni) {
    u32 n = cb + ni * 16 + (lane & 15);
#pragma unroll
    for (int ks = 0; ks < 4; ++ks)
      Bf[ni][ks] = *(const bf16x8*)(ldsB + (n << 8) + ((((u32)(ks * 4) + (lane >> 4)) ^ (n & 7)) << 4));
  }
#pragma unroll
  for (int mi = 0; mi < 4; ++mi) {
    u32 row = rb + mi * 16 + (lane & 15);
    bf16x8 Af[4];
#pragma unroll
    for (int ks = 0; ks < 4; ++ks)
      Af[ks] = *(const bf16x8*)(ldsA + (row << 8) + ((((u32)(ks * 4) + (lane >> 4)) ^ (row & 7)) << 4));
#pragma unroll
    for (int ni = 0; ni < 4; ++ni)
#pragma unroll
      for (int ks = 0; ks < 4; ++ks) acc[mi][ni] = mfma16(Af[ks], Bf[ni][ks], acc[mi][ni]);
  }
#pragma unroll
  for (int mi = 0; mi < 4; ++mi) {
    u32 rloc = rb + mi * 16 + ((lane >> 4) << 2);
#pragma unroll
    for (int j = 0; j < 4; ++j) {
      u32 rl = rloc + j;
      size_t grow = r0 + rl;
#pragma unroll
      for (int ni = 0; ni < 4; ++ni) {
        u32 col = cb + ni * 16 + (lane & 15);
        float v = acc[mi][ni][j];
        if (col < 128) {
          aggr[grow * 128 + col] = silu_f(v + bji[col]);
        } else {
          u32 c2 = col - 128;
          float rw = 0.f;
#pragma unroll
          for (int q = 0; q < 6; ++q) rw += ldsRbf[rl * 6 + q] * ldsWr[q * 128 + c2];
          ek[grow * 128 + c2] = f2bf(silu_f(v + bkj[c2]) * rw);
        }
      }
    }
  }
}

// ---------------------------------------------------------------------------
// S4: per block 128 ji-SORTED triplets (via tsort).
//   sp = sbf[tsort] @ Wsbf (in-block);  X = ek[kj] gather -> regs
//   acc[t][n] = sum_b sp[t][b] * (X @ WbilT[b])[t][n]
//   segmented in-LDS reduction over equal-ji runs, then one atomic per run.
__global__ __launch_bounds__(256, 2) void k_bil(
    const int* __restrict__ trip, const char* __restrict__ ek,
    const float* __restrict__ sbf, const float* __restrict__ Wsbf,
    const char* __restrict__ WbilT, const int* __restrict__ tsort,
    float* __restrict__ aggr) {
  extern __shared__ char lds[];
  char* buf0 = lds;                       // 32768 (sbf rows, then W even slices)
  char* buf1 = lds + 32768;               // 32768 (X gather, then W odd slices)
  float* msg = (float*)lds;               // [128][128] f32 overlay after b-loop
  float* spT = (float*)(lds + 65536);     // [8][128]
  int* kjl = (int*)(lds + 69632);         // 128
  int* jil = (int*)(lds + 70144);         // 128
  float* wsb = (float*)(lds + 70656);     // [42][8]
  const u32 tid = threadIdx.x, lane = tid & 63, wid = tid >> 6;
  const u32 t0 = blockIdx.x << 7;
  const u32 wm = wid >> 1, wn = wid & 1, rb = wm << 6, cb = wn << 6;

  // phase A: sorted indices + gathered sbf rows + Wsbf
  if (tid < 128) {
    int tv = tsort[t0 + tid];
    kjl[tid] = trip[tv];
    jil[tid] = trip[T_N + tv];
    const float* src = sbf + (size_t)tv * 42;
    float* drow = (float*)buf0 + tid * 42;
#pragma unroll
    for (int q = 0; q < 21; ++q)
      *(f32x2*)(drow + q * 2) = *(const f32x2*)(src + q * 2);
  } else if (tid < 212) {
    u32 i = tid - 128;
    ((f32x4*)wsb)[i] = ((const f32x4*)Wsbf)[i];
  }
  __syncthreads();

  // phase B: spT = sbf @ Wsbf ;  X gather -> buf1 (async, in flight)
  {
    const float* sbfl = (const float*)buf0;
    u32 row = tid >> 1, c4 = (tid & 1) * 4;
    float o0 = 0.f, o1 = 0.f, o2 = 0.f, o3 = 0.f;
#pragma unroll
    for (int q = 0; q < 42; ++q) {
      float r = sbfl[row * 42 + q];
      const float* w = wsb + q * 8 + c4;
      o0 += r * w[0]; o1 += r * w[1]; o2 += r * w[2]; o3 += r * w[3];
    }
    spT[(c4 + 0) * 128 + row] = o0;
    spT[(c4 + 1) * 128 + row] = o1;
    spT[(c4 + 2) * 128 + row] = o2;
    spT[(c4 + 3) * 128 + row] = o3;
  }
#pragma unroll
  for (int it = 0; it < 8; ++it) {
    u32 q = tid + it * 256, row = q >> 4, c = q & 15;
    gld_lds16(ek + (size_t)kjl[row] * 256 + ((c ^ (row & 7)) << 4), buf1 + q * 16);
  }
  WAIT_LGKM0();                       // buf0 (sbf) reads done before W0 overwrites
  __builtin_amdgcn_s_barrier();

  // phase C: stage W0 -> buf0; wait X+W0; hoist X fragments
#pragma unroll
  for (int it = 0; it < 8; ++it) {
    u32 q = tid + it * 256, n = q >> 4, c = q & 15;
    gld_lds16(WbilT + n * 256 + ((c ^ (n & 7)) << 4), buf0 + q * 16);
  }
  WAIT_VM0();
  __builtin_amdgcn_s_barrier();
  bf16x8 Afr[4][4];
#pragma unroll
  for (int mi = 0; mi < 4; ++mi) {
    u32 row = rb + mi * 16 + (lane & 15);
#pragma unroll
    for (int ks = 0; ks < 4; ++ks)
      Afr[mi][ks] = *(const bf16x8*)(buf1 + (row << 8) + ((((u32)(ks * 4) + (lane >> 4)) ^ (row & 7)) << 4));
  }

  // phase D: 8 b-slices; stage(next) overlaps MFMA; counted-drain structure.
  f32x4 acc[4][4] = {};
  for (int b = 0; b < 8; ++b) {
    char* cur = (b & 1) ? buf1 : buf0;
    char* nxt = (b & 1) ? buf0 : buf1;
    bf16x8 Bf[4][4];
#pragma unroll
    for (int ni = 0; ni < 4; ++ni) {
      u32 n = cb + ni * 16 + (lane & 15);
#pragma unroll
      for (int ks = 0; ks < 4; ++ks)
        Bf[ni][ks] = *(const bf16x8*)(cur + (n << 8) + ((((u32)(ks * 4) + (lane >> 4)) ^ (n & 7)) << 4));
    }
    WAIT_LGKM0();                     // all my LDS reads (Bf, Afr) complete
    __builtin_amdgcn_s_barrier();     // => everyone done reading nxt's old data
    if (b < 7) {
      const char* wsrc = WbilT + (size_t)(b + 1) * 32768;
#pragma unroll
      for (int it = 0; it < 8; ++it) {
        u32 q = tid + it * 256, n = q >> 4, c = q & 15;
        gld_lds16(wsrc + n * 256 + ((c ^ (n & 7)) << 4), nxt + q * 16);
      }
    }
#pragma unroll
    for (int mi = 0; mi < 4; ++mi) {
      f32x4 s4 = *(const f32x4*)(spT + b * 128 + rb + mi * 16 + ((lane >> 4) << 2));
#pragma unroll
      for (int ni = 0; ni < 4; ++ni) {
        f32x4 p = {0.f, 0.f, 0.f, 0.f};
#pragma unroll
        for (int ks = 0; ks < 4; ++ks) p = mfma16(Afr[mi][ks], Bf[ni][ks], p);
        acc[mi][ni] += s4 * p;
      }
    }
    if (b < 7) {
      WAIT_VM0();                     // next slice's W landed
      __builtin_amdgcn_s_barrier();
    }
  }

  // spill acc -> msg[128][128] (overlay buf0+buf1; all W reads barrier-retired)
#pragma unroll
  for (int mi = 0; mi < 4; ++mi) {
    u32 rloc = rb + mi * 16 + ((lane >> 4) << 2);
#pragma unroll
    for (int j = 0; j < 4; ++j) {
      float* drow = msg + (size_t)(rloc + j) * 128 + cb + (lane & 15);
#pragma unroll
      for (int ni = 0; ni < 4; ++ni) drow[ni * 16] = acc[mi][ni][j];
    }
  }
  __syncthreads();

  // segmented reduction over sorted-ji runs: one atomic per (run, col)
  if (tid < 128) {
    const u32 col = tid;
    float s = 0.f;
    for (int r = 0; r < 128; ++r) {
      s += msg[(size_t)r * 128 + col];
      int e = jil[r];
      if (r == 127 || jil[r + 1] != e) {
        unsafeAtomicAdd(&aggr[(size_t)e * 128 + col], s);
        s = 0.f;
      }
    }
  }
}

// ---------------------------------------------------------------------------
// S5: fused residual chain (unchanged).
__global__ __launch_bounds__(256, 2) void k_res(
    const float* __restrict__ aggr, const float* __restrict__ m,
    const char* __restrict__ rT,
    const float* __restrict__ rb1, const float* __restrict__ rb2,
    const float* __restrict__ rb3, const float* __restrict__ rb4,
    const float* __restrict__ bo, float* __restrict__ out) {
  extern __shared__ char lds[];
  char* ldsA = lds;
  char* ldsB = lds + 32768;
  const u32 tid = threadIdx.x, lane = tid & 63, wid = tid >> 6;
  const u32 r0 = blockIdx.x << 7;
  const u32 wm = wid >> 1, wn = wid & 1, rbw = wm << 6, cbw = wn << 6;
  const u32 lrow = (lane >> 4) << 2, lcol = lane & 15;

  auto stageB = [&](const char* WT) {
#pragma unroll
    for (int it = 0; it < 8; ++it) {
      u32 q = tid + it * 256, n = q >> 4, c = q & 15;
      gld_lds16(WT + n * 256 + ((c ^ (n & 7)) << 4), ldsB + q * 16);
    }
  };
  auto writeA = [&](u32 row, u32 col, float v) {
    *(u16*)(ldsA + (row << 8) + ((((col >> 3)) ^ (row & 7)) << 4) + (col & 7) * 2) = f2bf(v);
  };
  auto compute = [&](f32x4 (&acc)[4][4]) {
#pragma unroll
    for (int mi = 0; mi < 4; ++mi) {
      u32 row = rbw + mi * 16 + lcol;
      bf16x8 Af[4];
#pragma unroll
      for (int ks = 0; ks < 4; ++ks)
        Af[ks] = *(const bf16x8*)(ldsA + (row << 8) + ((((u32)(ks * 4) + (lane >> 4)) ^ (row & 7)) << 4));
#pragma unroll
      for (int ni = 0; ni < 4; ++ni) {
        u32 n = cbw + ni * 16 + lcol;
#pragma unroll
        for (int ks = 0; ks < 4; ++ks) {
          bf16x8 Bk = *(const bf16x8*)(ldsB + (n << 8) + ((((u32)(ks * 4) + (lane >> 4)) ^ (n & 7)) << 4));
          acc[mi][ni] = mfma16(Af[ks], Bk, acc[mi][ni]);
        }
      }
    }
  };
  auto zero = [&](f32x4 (&acc)[4][4]) {
#pragma unroll
    for (int a = 0; a < 4; ++a)
#pragma unroll
      for (int c = 0; c < 4; ++c) acc[a][c] = (f32x4){0.f, 0.f, 0.f, 0.f};
  };

  f32x4 xr[4][4];
#pragma unroll
  for (int mi = 0; mi < 4; ++mi)
#pragma unroll
    for (int j = 0; j < 4; ++j) {
      const float* src = aggr + (size_t)(r0 + rbw + mi * 16 + lrow + j) * 128 + cbw + lcol;
#pragma unroll
      for (int ni = 0; ni < 4; ++ni) xr[mi][ni][j] = src[ni * 16];
    }
  stageB(rT);
#pragma unroll
  for (int mi = 0; mi < 4; ++mi)
#pragma unroll
    for (int j = 0; j < 4; ++j) {
      u32 row = rbw + mi * 16 + lrow + j;
#pragma unroll
      for (int ni = 0; ni < 4; ++ni) writeA(row, cbw + ni * 16 + lcol, silu_f(xr[mi][ni][j]));
    }
  __syncthreads();

  f32x4 acc[4][4];
  zero(acc); compute(acc);
  __syncthreads();
#pragma unroll
  for (int mi = 0; mi < 4; ++mi)
#pragma unroll
    for (int j = 0; j < 4; ++j) {
      u32 row = rbw + mi * 16 + lrow + j;
#pragma unroll
      for (int ni = 0; ni < 4; ++ni) {
        u32 col = cbw + ni * 16 + lcol;
        writeA(row, col, silu_f(acc[mi][ni][j] + rb1[col]));
      }
    }
  stageB(rT + 32768);
  __syncthreads();

  zero(acc); compute(acc);
  __syncthreads();
#pragma unroll
  for (int mi = 0; mi < 4; ++mi)
#pragma unroll
    for (int j = 0; j < 4; ++j) {
      u32 row = rbw + mi * 16 + lrow + j;
#pragma unroll
      for (int ni = 0; ni < 4; ++ni) {
        u32 col = cbw + ni * 16 + lcol;
        xr[mi][ni][j] += acc[mi][ni][j] + rb2[col];
        writeA(row, col, silu_f(xr[mi][ni][j]));
      }
    }
  stageB(rT + 65536);
  __syncthreads();

  zero(acc); compute(acc);
  __syncthreads();
#pragma unroll
  for (int mi = 0; mi < 4; ++mi)
#pragma unroll
    for (int j = 0; j < 4; ++j) {
      u32 row = rbw + mi * 16 + lrow + j;
#pragma unroll
      for (int ni = 0; ni < 4; ++ni) {
        u32 col = cbw + ni * 16 + lcol;
        writeA(row, col, silu_f(acc[mi][ni][j] + rb3[col]));
      }
    }
  stageB(rT + 98304);
  __syncthreads();

  zero(acc); compute(acc);
  __syncthreads();
#pragma unroll
  for (int mi = 0; mi < 4; ++mi)
#pragma unroll
    for (int j = 0; j < 4; ++j) {
      u32 row = rbw + mi * 16 + lrow + j;
#pragma unroll
      for (int ni = 0; ni < 4; ++ni) {
        u32 col = cbw + ni * 16 + lcol;
        xr[mi][ni][j] += acc[mi][ni][j] + rb4[col];
        writeA(row, col, xr[mi][ni][j]);
      }
    }
  stageB(rT + 131072);
#pragma unroll
  for (int mi = 0; mi < 4; ++mi)
#pragma unroll
    for (int j = 0; j < 4; ++j) {
      const float* src = m + (size_t)(r0 + rbw + mi * 16 + lrow + j) * 128 + cbw + lcol;
#pragma unroll
      for (int ni = 0; ni < 4; ++ni) xr[mi][ni][j] = src[ni * 16];
    }
  __syncthreads();

  zero(acc); compute(acc);
#pragma unroll
  for (int mi = 0; mi < 4; ++mi)
#pragma unroll
    for (int j = 0; j < 4; ++j) {
      size_t grow = r0 + rbw + mi * 16 + lrow + j;
#pragma unroll
      for (int ni = 0; ni < 4; ++ni) {
        u32 col = cbw + ni * 16 + lcol;
        out[grow * 128 + col] = xr[mi][ni][j] + silu_f(acc[mi][ni][j] + bo[col]);
      }
    }
}

// ---------------------------------------------------------------------------
extern "C" void kernel_launch(void* const* d_in, const int* in_sizes, int n_in,
                              void* d_out, int out_size, void* d_ws, size_t ws_size,
                              hipStream_t stream) {
  const float* m = (const float*)d_in[0];
  const float* rbf = (const float*)d_in[1];
  const float* sbf = (const float*)d_in[2];
  const int* trip = (const int*)d_in[4];
  const float* Wrbf = (const float*)d_in[5];
  const float* Wsbf = (const float*)d_in[6];
  const float* bkj = (const float*)d_in[8];
  const float* bji = (const float*)d_in[10];
  const float* r1b1 = (const float*)d_in[13];
  const float* r1b2 = (const float*)d_in[15];
  const float* r2b1 = (const float*)d_in[17];
  const float* r2b2 = (const float*)d_in[19];
  const float* bout = (const float*)d_in[21];

  char* ws = (char*)d_ws;
  char* W2T = ws;                          // 65536 B
  char* WbilT = ws + 65536;                // 262144 B
  char* rT = ws + 327680;                  // 5 * 32768 B
  u16* ek = (u16*)(ws + 524288);           // E*128 bf16 (33.5 MB)
  float* aggr = (float*)(ws + 67633152);   // E*128 f32 (67 MB)
  int* cnt = (int*)(ws + 134742016);       // 131072 int
  int* offsA = (int*)(ws + 135266304);     // 131072 int
  int* blksum = (int*)(ws + 135790592);    // 512 int
  int* blkoff = (int*)(ws + 135792640);    // 512 int
  int* offs_work = (int*)(ws + 135794688); // 131072 int
  int* tsort = (int*)(ws + 136318976);     // T int (4 MB)

  hipFuncSetAttribute((const void*)k_pre, hipFuncAttributeMaxDynamicSharedMemorySize, 104448);
  hipFuncSetAttribute((const void*)k_bil, hipFuncAttributeMaxDynamicSharedMemorySize, 72000);
  hipFuncSetAttribute((const void*)k_res, hipFuncAttributeMaxDynamicSharedMemorySize, 65536);

  // triplet counting-sort by ji
  hipMemsetAsync(cnt, 0, 131072 * sizeof(int), stream);
  k_hist<<<4096, 256, 0, stream>>>(trip, cnt);
  k_scanA<<<512, 256, 0, stream>>>(cnt, offsA, blksum);
  k_scanB<<<1, 512, 0, stream>>>(blksum, blkoff);
  k_scanC<<<512, 256, 0, stream>>>(offsA, blkoff, offs_work);
  k_place<<<4096, 256, 0, stream>>>(trip, offs_work, tsort);

  k_transpose<<<960, 256, 0, stream>>>(
      (const float*)d_in[9], (const float*)d_in[7], (const float*)d_in[11],
      (const float*)d_in[12], (const float*)d_in[14], (const float*)d_in[16],
      (const float*)d_in[18], (const float*)d_in[20], (u16*)ws);
  k_pre<<<1024, 512, 104448, stream>>>(m, rbf, Wrbf, bkj, bji, W2T, aggr, ek);
  k_bil<<<8192, 256, 72000, stream>>>(trip, (const char*)ek, sbf, Wsbf, WbilT, tsort, aggr);
  k_res<<<1024, 256, 65536, stream>>>(aggr, m, rT, r1b1, r1b2, r2b1, r2b2, bout,
                                      (float*)d_out);
}